// Round 4
// baseline (401.871 us; speedup 1.0000x reference)
//
#include <hip/hip_runtime.h>
#include <math.h>

#define NBINS 256
#define NB2   (NBINS * NBINS)
#define HDIM  512
#define WDIM  512
#define NP    (HDIM * WDIM)
#define RRANGES 4
#define ROWS  (NBINS / RRANGES)   // 64 rows -> 64 KB LDS
#define SPLIT 4
#define TPB   1024
#define PI_F  3.14159265358979323846f

// grid = 768 blocks. Decode so the 4 range-blocks of one (hist,split) unit sit
// on the SAME XCD (id % 8) and are co-resident -> input chunk fetched into that
// XCD's L2 once, shared by all 4 ranges.
//   p = blockIdx.x; xcd = p&7; q = p>>3; rr = q&3; ul = q>>2 (0..23)
//   unit = xcd*24 + ul (0..191); hist = unit>>2; s = unit&3
__global__ __launch_bounds__(TPB) void hist_all(const float* __restrict__ X,
                                                float* __restrict__ out) {
    __shared__ float lh[ROWS * NBINS];   // 64 KB

    int p    = blockIdx.x;
    int xcd  = p & 7;
    int q    = p >> 3;
    int rr   = q & 3;
    int ul   = q >> 2;
    int unit = xcd * 24 + ul;
    int hist = unit >> 2;
    int s    = unit & 3;
    int b = hist / 6, ch = hist % 6;
    const int LO   = rr * ROWS;
    const int LOm1 = LO - 1;

    for (int k = threadIdx.x; k < ROWS * NBINS; k += TPB) lh[k] = 0.0f;
    __syncthreads();

    auto accum = [&](float a, float bvf, bool valid) {
        a = fminf(fmaxf(a, 0.0f), 255.0f);
        float fa = fminf(floorf(a), 254.0f);
        int   ix = (int)fa;
        if (valid && (unsigned)(ix - LOm1) <= (unsigned)ROWS) {
            float wxl = 0.5f * (1.0f + __cosf(PI_F * (a - fa)));
            float wxh = 1.0f - wxl;
            float bv = fminf(fmaxf(bvf, 0.0f), 255.0f);
            float fb = fminf(floorf(bv), 254.0f);
            int   iy = (int)fb;
            float wyl = 0.5f * (1.0f + __cosf(PI_F * (bv - fb)));
            float wyh = 1.0f - wyl;
            int r0 = ix - LO;
            if (r0 >= 0) {
                atomicAdd(&lh[r0 * NBINS + iy],     wxl * wyl);
                atomicAdd(&lh[r0 * NBINS + iy + 1], wxl * wyh);
            }
            if (r0 + 1 < ROWS) {
                atomicAdd(&lh[(r0 + 1) * NBINS + iy],     wxh * wyl);
                atomicAdd(&lh[(r0 + 1) * NBINS + iy + 1], wxh * wyh);
            }
        }
    };

    if (ch < 3) {
        // cband: pairs (X[b,ch,y,x], X[b,ch,y+1,x+1]), y,x in [0,511)
        // groups of 4 consecutive x: 128 groups/row, 511 rows = 65408 groups
        const float* plane = X + (size_t)(b * 3 + ch) * NP;
        const int GPP = 511 * 128;
        const int CH  = GPP / SPLIT;    // 16352
        int g1 = (s + 1) * CH;
        for (int g = s * CH + (int)threadIdx.x; g < g1; g += TPB) {
            int y  = g >> 7;
            int gx = g & 127;
            int x0 = gx << 2;
            const float4 va  = *(const float4*)(plane + y * WDIM + x0);
            const float4 vb4 = *(const float4*)(plane + (y + 1) * WDIM + x0);
            bool  t3 = (gx < 127);      // k=3 valid iff x0+3 < 511
            float bx = t3 ? plane[(y + 1) * WDIM + x0 + 4] : 0.0f;
            accum(va.x, vb4.y, true);
            accum(va.y, vb4.z, true);
            accum(va.z, vb4.w, true);
            accum(va.w, bx,    t3);
        }
    } else {
        // cc: pairs (X[b,ci,k], X[b,cj,k]) over all 512*512 pixels
        int pp = ch - 3;
        int ci = (pp == 2) ? 1 : 0;
        int cj = (pp == 0) ? 1 : 2;
        const float* pli = X + (size_t)(b * 3 + ci) * NP;
        const float* plj = X + (size_t)(b * 3 + cj) * NP;
        const int CH = (NP / 4) / SPLIT;   // 16384
        int g1 = (s + 1) * CH;
        for (int g = s * CH + (int)threadIdx.x; g < g1; g += TPB) {
            const float4 vi = *(const float4*)(pli + ((size_t)g << 2));
            const float4 vj = *(const float4*)(plj + ((size_t)g << 2));
            accum(vi.x, vj.x, true);
            accum(vi.y, vj.y, true);
            accum(vi.z, vj.z, true);
            accum(vi.w, vj.w, true);
        }
    }

    __syncthreads();
    // Flush: SPLIT blocks share each (hist, range) -> coalesced global atomics
    float* dst = out + (size_t)hist * NB2 + LO * NBINS;
    const float4* lh4 = (const float4*)lh;
    for (int k = threadIdx.x; k < ROWS * NBINS / 4; k += TPB) {
        float4 v = lh4[k];
        int o = k * 4;
        atomicAdd(&dst[o],     v.x);
        atomicAdd(&dst[o + 1], v.y);
        atomicAdd(&dst[o + 2], v.z);
        atomicAdd(&dst[o + 3], v.w);
    }
}

__global__ __launch_bounds__(1024) void max_reduce(const float* __restrict__ out,
                                                   float* __restrict__ vmax) {
    int ch = blockIdx.x;   // 0..47
    const float4* h = (const float4*)(out + (size_t)ch * NB2);
    float m = 0.0f;
    for (int i = threadIdx.x; i < NB2 / 4; i += blockDim.x) {
        float4 v = h[i];
        m = fmaxf(m, fmaxf(fmaxf(v.x, v.y), fmaxf(v.z, v.w)));
    }
    for (int off = 32; off; off >>= 1) m = fmaxf(m, __shfl_down(m, off));
    __shared__ float sred[16];
    int lane = threadIdx.x & 63, wid = threadIdx.x >> 6;
    if (lane == 0) sred[wid] = m;
    __syncthreads();
    if (threadIdx.x == 0) {
        float mm = sred[0];
        int nw = blockDim.x >> 6;
        for (int w = 1; w < nw; ++w) mm = fmaxf(mm, sred[w]);
        vmax[ch] = mm;
    }
}

__global__ void normalize(float* __restrict__ out, const float* __restrict__ vmax) {
    const int total4 = 48 * NB2 / 4;
    int stride = gridDim.x * blockDim.x;
    float4* o4 = (float4*)out;
    for (int i = blockIdx.x * blockDim.x + threadIdx.x; i < total4; i += stride) {
        int ch = i >> 14;
        float inv = 1.0f / vmax[ch];
        float4 v = o4[i];
        v.x *= inv; v.y *= inv; v.z *= inv; v.w *= inv;
        o4[i] = v;
    }
}

extern "C" void kernel_launch(void* const* d_in, const int* in_sizes, int n_in,
                              void* d_out, int out_size, void* d_ws, size_t ws_size,
                              hipStream_t stream) {
    const float* X = (const float*)d_in[0];
    float* out = (float*)d_out;
    float* vmax = (float*)d_ws;

    hipMemsetAsync(d_out, 0, (size_t)out_size * sizeof(float), stream);

    hist_all<<<48 * RRANGES * SPLIT, TPB, 0, stream>>>(X, out);
    max_reduce<<<48, 1024, 0, stream>>>(out, vmax);
    normalize<<<1024, 256, 0, stream>>>(out, vmax);
}

// Round 5
// 139.490 us; speedup vs baseline: 2.8810x; 2.8810x over previous
//
#include <hip/hip_runtime.h>
#include <math.h>

#define NBINS 256
#define NB2   (NBINS * NBINS)
#define HDIM  512
#define WDIM  512
#define NP    (HDIM * WDIM)
#define SPLIT 5
#define TPB   1024
#define SCALE     2048.0f
#define INV_SCALE (1.0f / 2048.0f)
#define PI_F  3.14159265358979323846f

// One block builds a FULL 256x256 histogram in LDS as u16 fixed-point (x2048),
// two y-adjacent bins packed per u32 so one ds_add_u32 covers both y-neighbors.
// grid = 240: id&7 = batch (one batch per XCD -> 3 MB input L2-resident, and the
// 5 split-blocks of one hist flush within one XCD's L2 -> no cross-XCD ping-pong).
__global__ __launch_bounds__(TPB) void hist_all(const float* __restrict__ X,
                                                float* __restrict__ out) {
    __shared__ unsigned int lh[NB2 / 2];   // 128 KB

    int id = blockIdx.x;
    int b  = id & 7;           // batch == XCD
    int t  = id >> 3;          // 0..29
    int s  = t % SPLIT;
    int ch = t / SPLIT;        // 0..5
    int hist = b * 6 + ch;

    for (int k = threadIdx.x; k < NB2 / 2; k += TPB) lh[k] = 0u;
    __syncthreads();

    auto accum = [&](float a, float bv) {
        a = fminf(fmaxf(a, 0.0f), 255.0f);
        float fa = fminf(floorf(a), 254.0f);
        int   ix = (int)fa;
        float wxl = 0.5f * (1.0f + __cosf(PI_F * (a - fa)));
        float wxh = 1.0f - wxl;
        bv = fminf(fmaxf(bv, 0.0f), 255.0f);
        float fb = fminf(floorf(bv), 254.0f);
        int   iy = (int)fb;
        float wyl = 0.5f * (1.0f + __cosf(PI_F * (bv - fb)));
        float wyh = 1.0f - wyl;
        float ylS = wyl * SCALE, yhS = wyh * SCALE;

        unsigned e = (unsigned)iy & 1u;
        int u = (ix * NBINS + iy) >> 1;
        // row ix: q0 -> slot iy, q1 -> slot iy+1
        unsigned q0 = (unsigned)(wxl * ylS + 0.5f);
        unsigned q1 = (unsigned)(wxl * yhS + 0.5f);
        atomicAdd(&lh[u], e ? (q0 << 16) : (q0 | (q1 << 16)));
        if (e) atomicAdd(&lh[u + 1], q1);
        // row ix+1: +256 slots = +128 u32s, same parity
        unsigned r0 = (unsigned)(wxh * ylS + 0.5f);
        unsigned r1 = (unsigned)(wxh * yhS + 0.5f);
        atomicAdd(&lh[u + 128], e ? (r0 << 16) : (r0 | (r1 << 16)));
        if (e) atomicAdd(&lh[u + 129], r1);
    };

    if (ch < 3) {
        // cband: pairs (X[b,ch,y,x], X[b,ch,y+1,x+1]), y,x in [0,511)
        const float* plane = X + (size_t)(b * 3 + ch) * NP;
        const int NG = 511 * 128;                 // 4-wide x-groups
        const int CG = (NG + SPLIT - 1) / SPLIT;  // 13082
        int hi = min(NG, (s + 1) * CG);
        for (int g = s * CG + (int)threadIdx.x; g < hi; g += TPB) {
            int y  = g >> 7;
            int gx = g & 127;
            int x0 = gx << 2;
            const float4 va = *(const float4*)(plane + y * WDIM + x0);
            const float4 vb = *(const float4*)(plane + (y + 1) * WDIM + x0);
            bool t3 = (gx < 127);
            float bx = t3 ? plane[(y + 1) * WDIM + x0 + 4] : 0.0f;
            accum(va.x, vb.y);
            accum(va.y, vb.z);
            accum(va.z, vb.w);
            if (t3) accum(va.w, bx);
        }
    } else {
        // cc: pairs (X[b,ci,k], X[b,cj,k]) over all pixels
        int pp = ch - 3;
        int ci = (pp == 2) ? 1 : 0;
        int cj = (pp == 0) ? 1 : 2;
        const float* pli = X + (size_t)(b * 3 + ci) * NP;
        const float* plj = X + (size_t)(b * 3 + cj) * NP;
        const int NG = NP / 4;                    // 65536
        const int CG = (NG + SPLIT - 1) / SPLIT;  // 13108
        int hi = min(NG, (s + 1) * CG);
        for (int g = s * CG + (int)threadIdx.x; g < hi; g += TPB) {
            const float4 vi = *(const float4*)(pli + ((size_t)g << 2));
            const float4 vj = *(const float4*)(plj + ((size_t)g << 2));
            accum(vi.x, vj.x);
            accum(vi.y, vj.y);
            accum(vi.z, vj.z);
            accum(vi.w, vj.w);
        }
    }

    __syncthreads();
    // Flush: 5 split-blocks atomically merge into d_out (same-XCD L2).
    float* dst = out + (size_t)hist * NB2;
    for (int k = threadIdx.x; k < NB2 / 2; k += TPB) {
        unsigned v = lh[k];
        atomicAdd(&dst[2 * k],     (float)(v & 0xFFFFu) * INV_SCALE);
        atomicAdd(&dst[2 * k + 1], (float)(v >> 16)     * INV_SCALE);
    }
}

__global__ __launch_bounds__(1024) void max_reduce(const float* __restrict__ out,
                                                   float* __restrict__ vmax) {
    int ch = blockIdx.x;   // 0..47
    const float4* h = (const float4*)(out + (size_t)ch * NB2);
    float m = 0.0f;
    for (int i = threadIdx.x; i < NB2 / 4; i += blockDim.x) {
        float4 v = h[i];
        m = fmaxf(m, fmaxf(fmaxf(v.x, v.y), fmaxf(v.z, v.w)));
    }
    for (int off = 32; off; off >>= 1) m = fmaxf(m, __shfl_down(m, off));
    __shared__ float sred[16];
    int lane = threadIdx.x & 63, wid = threadIdx.x >> 6;
    if (lane == 0) sred[wid] = m;
    __syncthreads();
    if (threadIdx.x == 0) {
        float mm = sred[0];
        int nw = blockDim.x >> 6;
        for (int w = 1; w < nw; ++w) mm = fmaxf(mm, sred[w]);
        vmax[ch] = mm;
    }
}

__global__ void normalize(float* __restrict__ out, const float* __restrict__ vmax) {
    const int total4 = 48 * NB2 / 4;
    int stride = gridDim.x * blockDim.x;
    float4* o4 = (float4*)out;
    for (int i = blockIdx.x * blockDim.x + threadIdx.x; i < total4; i += stride) {
        int ch = i >> 14;
        float inv = 1.0f / vmax[ch];
        float4 v = o4[i];
        v.x *= inv; v.y *= inv; v.z *= inv; v.w *= inv;
        o4[i] = v;
    }
}

extern "C" void kernel_launch(void* const* d_in, const int* in_sizes, int n_in,
                              void* d_out, int out_size, void* d_ws, size_t ws_size,
                              hipStream_t stream) {
    const float* X = (const float*)d_in[0];
    float* out = (float*)d_out;
    float* vmax = (float*)d_ws;

    hipMemsetAsync(d_out, 0, (size_t)out_size * sizeof(float), stream);

    hist_all<<<48 * SPLIT, TPB, 0, stream>>>(X, out);
    max_reduce<<<48, 1024, 0, stream>>>(out, vmax);
    normalize<<<1024, 256, 0, stream>>>(out, vmax);
}

// Round 6
// 42.925 us; speedup vs baseline: 9.3622x; 3.2496x over previous
//
#include <hip/hip_runtime.h>
#include <math.h>

#define NBINS 256
#define NB2   (NBINS * NBINS)
#define HDIM  512
#define WDIM  512
#define NP    (HDIM * WDIM)
#define SPLIT 5
#define TPB   1024
#define SCALE     2048.0f
#define INV_SCALE (1.0f / 2048.0f)
#define PI_F  3.14159265358979323846f
#define PART_U32 (NB2 / 2)                        // 32768 u32 per partial
#define WS_NEEDED ((size_t)48 * SPLIT * PART_U32 * 4)   // 31.5 MB

// ---------------- scatter: full 256x256 hist in LDS, packed u16 x2048 ----------------
// grid = 240: id&7 = batch (one batch per XCD -> input planes L2-resident; the 5
// split-partials of one hist are written & later merged on the same XCD).
template <bool TO_WS>
__global__ __launch_bounds__(TPB) void hist_all(const float* __restrict__ X,
                                                float* __restrict__ out,
                                                unsigned* __restrict__ ws) {
    __shared__ unsigned int lh[PART_U32];   // 128 KB

    int id = blockIdx.x;
    int b  = id & 7;           // batch == XCD
    int t  = id >> 3;          // 0..29
    int s  = t % SPLIT;
    int ch = t / SPLIT;        // 0..5
    int hist = b * 6 + ch;

    for (int k = threadIdx.x; k < PART_U32; k += TPB) lh[k] = 0u;
    __syncthreads();

    auto accum = [&](float a, float bv) {
        a = fminf(fmaxf(a, 0.0f), 255.0f);
        float fa = fminf(floorf(a), 254.0f);
        int   ix = (int)fa;
        float wxl = 0.5f * (1.0f + __cosf(PI_F * (a - fa)));
        float wxh = 1.0f - wxl;
        bv = fminf(fmaxf(bv, 0.0f), 255.0f);
        float fb = fminf(floorf(bv), 254.0f);
        int   iy = (int)fb;
        float wyl = 0.5f * (1.0f + __cosf(PI_F * (bv - fb)));
        float wyh = 1.0f - wyl;
        float ylS = wyl * SCALE, yhS = wyh * SCALE;

        unsigned e = (unsigned)iy & 1u;
        int u = (ix * NBINS + iy) >> 1;
        unsigned q0 = (unsigned)(wxl * ylS + 0.5f);
        unsigned q1 = (unsigned)(wxl * yhS + 0.5f);
        atomicAdd(&lh[u], e ? (q0 << 16) : (q0 | (q1 << 16)));
        if (e) atomicAdd(&lh[u + 1], q1);
        unsigned r0 = (unsigned)(wxh * ylS + 0.5f);
        unsigned r1 = (unsigned)(wxh * yhS + 0.5f);
        atomicAdd(&lh[u + 128], e ? (r0 << 16) : (r0 | (r1 << 16)));
        if (e) atomicAdd(&lh[u + 129], r1);
    };

    if (ch < 3) {
        // cband: pairs (X[b,ch,y,x], X[b,ch,y+1,x+1]), y,x in [0,511)
        const float* plane = X + (size_t)(b * 3 + ch) * NP;
        const int NG = 511 * 128;                 // 4-wide x-groups
        const int CG = (NG + SPLIT - 1) / SPLIT;
        int hi = min(NG, (s + 1) * CG);
        for (int g = s * CG + (int)threadIdx.x; g < hi; g += TPB) {
            int y  = g >> 7;
            int gx = g & 127;
            int x0 = gx << 2;
            const float4 va = *(const float4*)(plane + y * WDIM + x0);
            const float4 vb = *(const float4*)(plane + (y + 1) * WDIM + x0);
            bool t3 = (gx < 127);
            float bx = t3 ? plane[(y + 1) * WDIM + x0 + 4] : 0.0f;
            accum(va.x, vb.y);
            accum(va.y, vb.z);
            accum(va.z, vb.w);
            if (t3) accum(va.w, bx);
        }
    } else {
        // cc: pairs (X[b,ci,k], X[b,cj,k])
        int pp = ch - 3;
        int ci = (pp == 2) ? 1 : 0;
        int cj = (pp == 0) ? 1 : 2;
        const float* pli = X + (size_t)(b * 3 + ci) * NP;
        const float* plj = X + (size_t)(b * 3 + cj) * NP;
        const int NG = NP / 4;
        const int CG = (NG + SPLIT - 1) / SPLIT;
        int hi = min(NG, (s + 1) * CG);
        for (int g = s * CG + (int)threadIdx.x; g < hi; g += TPB) {
            const float4 vi = *(const float4*)(pli + ((size_t)g << 2));
            const float4 vj = *(const float4*)(plj + ((size_t)g << 2));
            accum(vi.x, vj.x);
            accum(vi.y, vj.y);
            accum(vi.z, vj.z);
            accum(vi.w, vj.w);
        }
    }

    __syncthreads();
    if (TO_WS) {
        // Streaming store of the packed partial (no RMW, coalesced uint4).
        uint4* dst = (uint4*)(ws + (size_t)(hist * SPLIT + s) * PART_U32);
        const uint4* src = (const uint4*)lh;
        for (int k = threadIdx.x; k < PART_U32 / 4; k += TPB) dst[k] = src[k];
    } else {
        // Fallback: atomic merge into d_out (requires pre-zeroed d_out).
        float* dst = out + (size_t)hist * NB2;
        for (int k = threadIdx.x; k < PART_U32; k += TPB) {
            unsigned v = lh[k];
            atomicAdd(&dst[2 * k],     (float)(v & 0xFFFFu) * INV_SCALE);
            atomicAdd(&dst[2 * k + 1], (float)(v >> 16)     * INV_SCALE);
        }
    }
}

// ---------------- merge: sum 5 packed partials, max-normalize, write ----------------
// grid = 48; id&7 = batch -> same XCD as the partials' producers (L2 hits).
// Packed sum is carry-safe: summed low halves = full-hist scaled count (< 65536).
__global__ __launch_bounds__(TPB) void merge48(const unsigned* __restrict__ ws,
                                               float* __restrict__ out) {
    int b = blockIdx.x & 7, ch = blockIdx.x >> 3;
    int hist = b * 6 + ch;
    const unsigned* p = ws + (size_t)hist * SPLIT * PART_U32;

    unsigned sums[32];
    unsigned mx = 0;
#pragma unroll
    for (int t = 0; t < 32; ++t) {
        int k = (int)threadIdx.x + (t << 10);
        unsigned v = p[k] + p[PART_U32 + k] + p[2 * PART_U32 + k]
                   + p[3 * PART_U32 + k] + p[4 * PART_U32 + k];
        sums[t] = v;
        mx = max(mx, max(v & 0xFFFFu, v >> 16));
    }
    // block max reduce
    for (int off = 32; off; off >>= 1)
        mx = max(mx, (unsigned)__shfl_down((int)mx, off));
    __shared__ unsigned sred[16];
    int lane = threadIdx.x & 63, wid = threadIdx.x >> 6;
    if (lane == 0) sred[wid] = mx;
    __syncthreads();
    if (threadIdx.x == 0) {
        unsigned m = sred[0];
        for (int w = 1; w < 16; ++w) m = max(m, sred[w]);
        sred[0] = m;
    }
    __syncthreads();
    float inv = 1.0f / (float)sred[0];   // scale cancels: out = count / maxcount

    float2* o2 = (float2*)(out + (size_t)hist * NB2);
#pragma unroll
    for (int t = 0; t < 32; ++t) {
        int k = (int)threadIdx.x + (t << 10);
        unsigned v = sums[t];
        float2 r;
        r.x = (float)(v & 0xFFFFu) * inv;
        r.y = (float)(v >> 16)     * inv;
        o2[k] = r;
    }
}

// ---------------- fallback epilogue (ws too small) ----------------
__global__ __launch_bounds__(1024) void max_reduce(const float* __restrict__ out,
                                                   float* __restrict__ vmax) {
    int ch = blockIdx.x;
    const float4* h = (const float4*)(out + (size_t)ch * NB2);
    float m = 0.0f;
    for (int i = threadIdx.x; i < NB2 / 4; i += blockDim.x) {
        float4 v = h[i];
        m = fmaxf(m, fmaxf(fmaxf(v.x, v.y), fmaxf(v.z, v.w)));
    }
    for (int off = 32; off; off >>= 1) m = fmaxf(m, __shfl_down(m, off));
    __shared__ float sred[16];
    int lane = threadIdx.x & 63, wid = threadIdx.x >> 6;
    if (lane == 0) sred[wid] = m;
    __syncthreads();
    if (threadIdx.x == 0) {
        float mm = sred[0];
        int nw = blockDim.x >> 6;
        for (int w = 1; w < nw; ++w) mm = fmaxf(mm, sred[w]);
        vmax[ch] = mm;
    }
}

__global__ void normalize(float* __restrict__ out, const float* __restrict__ vmax) {
    const int total4 = 48 * NB2 / 4;
    int stride = gridDim.x * blockDim.x;
    float4* o4 = (float4*)out;
    for (int i = blockIdx.x * blockDim.x + threadIdx.x; i < total4; i += stride) {
        int ch = i >> 14;
        float inv = 1.0f / vmax[ch];
        float4 v = o4[i];
        v.x *= inv; v.y *= inv; v.z *= inv; v.w *= inv;
        o4[i] = v;
    }
}

extern "C" void kernel_launch(void* const* d_in, const int* in_sizes, int n_in,
                              void* d_out, int out_size, void* d_ws, size_t ws_size,
                              hipStream_t stream) {
    const float* X = (const float*)d_in[0];
    float* out = (float*)d_out;

    if (ws_size >= WS_NEEDED) {
        unsigned* ws = (unsigned*)d_ws;
        hist_all<true><<<48 * SPLIT, TPB, 0, stream>>>(X, out, ws);
        merge48<<<48, TPB, 0, stream>>>(ws, out);
    } else {
        float* vmax = (float*)d_ws;
        hipMemsetAsync(d_out, 0, (size_t)out_size * sizeof(float), stream);
        hist_all<false><<<48 * SPLIT, TPB, 0, stream>>>(X, out, nullptr);
        max_reduce<<<48, 1024, 0, stream>>>(out, vmax);
        normalize<<<1024, 256, 0, stream>>>(out, vmax);
    }
}